// Round 1
// baseline (2576.226 us; speedup 1.0000x reference)
//
#include <hip/hip_runtime.h>
#include <hip/hip_bf16.h>

// GCN encoder: 2x GCNConv with symmetric normalization, relu + L2 rownorm between.
// Strategy: build CSR-by-dst once per launch (histogram + scan + fill), then
// pull-style aggregation (no float atomics). GEMMs in f32 with LDS tiling.

#define N_NODES_MAX 100096
#define IN_CH 128
#define HID 128
#define OUT_CH 64

// ---------------- degree histogram ----------------
__global__ __launch_bounds__(256) void count_kernel(const int* __restrict__ dst,
                                                    int E, int* __restrict__ cnt) {
    int e = blockIdx.x * 256 + threadIdx.x;
    if (e < E) atomicAdd(&cnt[dst[e]], 1);
}

// ---------------- 3-kernel exclusive scan over cnt[] -> row_start[] ----------------
__global__ __launch_bounds__(256) void scan1_kernel(const int* __restrict__ cnt, int n,
                                                    int* __restrict__ row_start,
                                                    int* __restrict__ bsum) {
    __shared__ int sdata[256];
    int tid = threadIdx.x;
    int i = blockIdx.x * 256 + tid;
    int v = (i < n) ? cnt[i] : 0;
    sdata[tid] = v;
    __syncthreads();
    for (int off = 1; off < 256; off <<= 1) {
        int t = (tid >= off) ? sdata[tid - off] : 0;
        __syncthreads();
        sdata[tid] += t;
        __syncthreads();
    }
    if (i < n) row_start[i] = sdata[tid] - v;  // exclusive, block-local
    if (tid == 255) bsum[blockIdx.x] = sdata[255];
}

__global__ __launch_bounds__(512) void scan2_kernel(int* __restrict__ bsum, int nb,
                                                    int* __restrict__ boff) {
    __shared__ int sdata[512];
    int tid = threadIdx.x;
    int v = (tid < nb) ? bsum[tid] : 0;
    sdata[tid] = v;
    __syncthreads();
    for (int off = 1; off < 512; off <<= 1) {
        int t = (tid >= off) ? sdata[tid - off] : 0;
        __syncthreads();
        sdata[tid] += t;
        __syncthreads();
    }
    boff[tid] = sdata[tid] - v;  // exclusive
}

__global__ __launch_bounds__(256) void scan3_kernel(int* __restrict__ row_start,
                                                    const int* __restrict__ boff,
                                                    const int* __restrict__ cnt,
                                                    int* __restrict__ cursor,
                                                    float* __restrict__ dinv,
                                                    int n, int E) {
    int i = blockIdx.x * 256 + threadIdx.x;
    if (i < n) {
        int rs = row_start[i] + boff[i >> 8];
        row_start[i] = rs;
        cursor[i] = rs;
        dinv[i] = rsqrtf((float)(cnt[i] + 1));  // +1 self loop
    }
    if (i == 0) row_start[n] = E;
}

// ---------------- CSR fill ----------------
__global__ __launch_bounds__(256) void fill_kernel(const int* __restrict__ src,
                                                   const int* __restrict__ dst,
                                                   int E, int* __restrict__ cursor,
                                                   int* __restrict__ csr_src) {
    int e = blockIdx.x * 256 + threadIdx.x;
    if (e < E) {
        int d = dst[e];
        int p = atomicAdd(&cursor[d], 1);
        csr_src[p] = src[e];
    }
}

// ---------------- GEMM: Y[n x NCOL] = X[n x 128] * W[128 x NCOL] ----------------
template <int NCOL>
__global__ __launch_bounds__(256) void gemm_kernel(const float* __restrict__ X,
                                                   const float* __restrict__ W,
                                                   float* __restrict__ Y, int nrows) {
    constexpr int K = 128;
    constexpr int KT = 32;               // K-tile for W staging
    constexpr int CT = NCOL / 4;         // col-threads
    constexpr int RT = 256 / CT;         // row-threads
    constexpr int RPT = 64 / RT;         // rows per thread
    __shared__ __align__(16) float Ws[KT * NCOL];   // 16 KB (NCOL=128) / 8 KB
    __shared__ __align__(16) float Xs[64 * K];      // 32 KB
    int tid = threadIdx.x;
    int rowBase = blockIdx.x * 64;

    // load X tile (64 rows x 128), coalesced float4
    {
        float4* Xs4 = (float4*)Xs;
        const float4* X4 = (const float4*)X;
        #pragma unroll
        for (int j = tid; j < 64 * K / 4; j += 256) {
            int r = j >> 5;       // /(K/4)=32
            int c4 = j & 31;
            int gr = rowBase + r;
            float4 v = make_float4(0.f, 0.f, 0.f, 0.f);
            if (gr < nrows) v = X4[(size_t)gr * 32 + c4];
            Xs4[j] = v;
        }
    }

    int tx = tid % CT;
    int ty = tid / CT;
    int c0 = tx * 4;
    int r0 = ty * RPT;
    float4 acc[RPT];
    #pragma unroll
    for (int i = 0; i < RPT; i++) acc[i] = make_float4(0.f, 0.f, 0.f, 0.f);

    for (int kt = 0; kt < K; kt += KT) {
        __syncthreads();
        // stage W k-tile
        {
            float4* Ws4 = (float4*)Ws;
            const float4* W4 = (const float4*)W;
            #pragma unroll
            for (int j = tid; j < KT * NCOL / 4; j += 256)
                Ws4[j] = W4[(size_t)kt * (NCOL / 4) + j];
        }
        __syncthreads();
        for (int k2 = 0; k2 < KT; k2++) {
            float4 w = *(const float4*)&Ws[k2 * NCOL + c0];
            #pragma unroll
            for (int i = 0; i < RPT; i++) {
                float xv = Xs[(r0 + i) * K + kt + k2];
                acc[i].x = fmaf(xv, w.x, acc[i].x);
                acc[i].y = fmaf(xv, w.y, acc[i].y);
                acc[i].z = fmaf(xv, w.z, acc[i].z);
                acc[i].w = fmaf(xv, w.w, acc[i].w);
            }
        }
    }

    #pragma unroll
    for (int i = 0; i < RPT; i++) {
        int gr = rowBase + r0 + i;
        if (gr < nrows) *(float4*)&Y[(size_t)gr * NCOL + c0] = acc[i];
    }
}

// ---------------- aggregation layer 1: pull + bias + relu + L2 rownorm ----------------
__global__ __launch_bounds__(256) void agg1_kernel(const float* __restrict__ xw,
                                                   const int* __restrict__ csr_src,
                                                   const int* __restrict__ row_start,
                                                   const float* __restrict__ dinv,
                                                   const float* __restrict__ b1,
                                                   float* __restrict__ h, int n) {
    int wid = (blockIdx.x * 256 + threadIdx.x) >> 6;  // one wave per node
    int lane = threadIdx.x & 63;
    if (wid >= n) return;
    int i = wid;
    float di = dinv[i];
    float sc = di * di;  // self-loop coef
    const float2* selfrow = (const float2*)(xw + (size_t)i * HID);
    float2 sv = selfrow[lane];
    float ax = sv.x * sc, ay = sv.y * sc;
    int e0 = row_start[i], e1 = row_start[i + 1];
    for (int e = e0; e < e1; e++) {
        int s = csr_src[e];
        float w = dinv[s] * di;
        float2 v = ((const float2*)(xw + (size_t)s * HID))[lane];
        ax = fmaf(v.x, w, ax);
        ay = fmaf(v.y, w, ay);
    }
    ax += b1[lane * 2];
    ay += b1[lane * 2 + 1];
    ax = fmaxf(ax, 0.f);
    ay = fmaxf(ay, 0.f);
    float ss = ax * ax + ay * ay;
    #pragma unroll
    for (int m = 32; m >= 1; m >>= 1) ss += __shfl_xor(ss, m, 64);
    float norm = sqrtf(ss);
    float scale = 1.0f / fmaxf(norm, 1e-12f);
    ((float2*)(h + (size_t)i * HID))[lane] = make_float2(ax * scale, ay * scale);
}

// ---------------- aggregation layer 2: pull + bias -> d_out ----------------
__global__ __launch_bounds__(256) void agg2_kernel(const float* __restrict__ hw,
                                                   const int* __restrict__ csr_src,
                                                   const int* __restrict__ row_start,
                                                   const float* __restrict__ dinv,
                                                   const float* __restrict__ b2,
                                                   float* __restrict__ out, int n) {
    int wid = (blockIdx.x * 256 + threadIdx.x) >> 6;  // one wave per node
    int lane = threadIdx.x & 63;
    if (wid >= n) return;
    int i = wid;
    float di = dinv[i];
    float sc = di * di;
    float a = hw[(size_t)i * OUT_CH + lane] * sc;
    int e0 = row_start[i], e1 = row_start[i + 1];
    for (int e = e0; e < e1; e++) {
        int s = csr_src[e];
        float w = dinv[s] * di;
        a = fmaf(hw[(size_t)s * OUT_CH + lane], w, a);
    }
    a += b2[lane];
    out[(size_t)i * OUT_CH + lane] = a;
}

extern "C" void kernel_launch(void* const* d_in, const int* in_sizes, int n_in,
                              void* d_out, int out_size, void* d_ws, size_t ws_size,
                              hipStream_t stream) {
    const float* x  = (const float*)d_in[0];
    const int*   ei = (const int*)d_in[1];   // [2 x E] int32 per harness convention
    const float* W1 = (const float*)d_in[2];
    const float* b1 = (const float*)d_in[3];
    const float* W2 = (const float*)d_in[4];
    const float* b2 = (const float*)d_in[5];
    float* out = (float*)d_out;

    const int N = in_sizes[0] / IN_CH;     // 100000
    const int E = in_sizes[1] / 2;         // 1600000
    const int* src = ei;
    const int* dst = ei + E;

    // ---- workspace carve (all 256B aligned) ----
    char* base = (char*)d_ws;
    size_t off = 0;
    auto alloc = [&](size_t bytes) -> void* {
        void* p = base + off;
        off = (off + bytes + 255) & ~(size_t)255;
        return p;
    };
    int*   cnt       = (int*)alloc((size_t)N * 4);
    int*   row_start = (int*)alloc((size_t)(N + 1) * 4);
    int*   cursor    = (int*)alloc((size_t)N * 4);
    int*   bsum      = (int*)alloc(512 * 4);
    int*   boff      = (int*)alloc(512 * 4);
    float* dinv      = (float*)alloc((size_t)N * 4);
    int*   csr_src   = (int*)alloc((size_t)E * 4);
    float* xw        = (float*)alloc((size_t)N * HID * 4);
    float* h         = (float*)alloc((size_t)N * HID * 4);
    float* hw        = (float*)alloc((size_t)N * OUT_CH * 4);
    (void)ws_size;

    const int nb = (N + 255) / 256;  // scan blocks (391)

    // 1) degree histogram
    hipMemsetAsync(cnt, 0, (size_t)N * 4, stream);
    count_kernel<<<(E + 255) / 256, 256, 0, stream>>>(dst, E, cnt);

    // 2) exclusive scan -> row_start; dinv; cursor
    scan1_kernel<<<nb, 256, 0, stream>>>(cnt, N, row_start, bsum);
    scan2_kernel<<<1, 512, 0, stream>>>(bsum, nb, boff);
    scan3_kernel<<<nb, 256, 0, stream>>>(row_start, boff, cnt, cursor, dinv, N, E);

    // 3) CSR fill
    fill_kernel<<<(E + 255) / 256, 256, 0, stream>>>(src, dst, E, cursor, csr_src);

    // 4) GEMM1: xw = x @ W1
    gemm_kernel<128><<<(N + 63) / 64, 256, 0, stream>>>(x, W1, xw, N);

    // 5) aggregate + bias + relu + rownorm -> h
    agg1_kernel<<<(N * 64 + 255) / 256, 256, 0, stream>>>(xw, csr_src, row_start, dinv, b1, h, N);

    // 6) GEMM2: hw = h @ W2
    gemm_kernel<64><<<(N + 63) / 64, 256, 0, stream>>>(h, W2, hw, N);

    // 7) aggregate + bias -> out
    agg2_kernel<<<(N * 64 + 255) / 256, 256, 0, stream>>>(hw, csr_src, row_start, dinv, b2, out, N);
}

// Round 2
// 724.511 us; speedup vs baseline: 3.5558x; 3.5558x over previous
//
#include <hip/hip_runtime.h>
#include <hip/hip_bf16.h>

// GCN encoder: 2x GCNConv with symmetric normalization, relu + L2 rownorm between.
// Strategy: build CSR-by-dst once per launch (histogram + scan + fill), then
// pull-style aggregation (no float atomics). GEMMs in f32 with LDS tiling.
//
// R1 fix: previous gemm spilled (VGPR=256, 1.6GB scratch writes, 1945us).
// New gemm: wave-per-16-rows, lane-per-(NCOL/64)-cols, Xs read is a
// same-address LDS broadcast (float4), bounded live set, launch_bounds(256,3).

#define IN_CH 128
#define HID 128
#define OUT_CH 64

// ---------------- degree histogram ----------------
__global__ __launch_bounds__(256) void count_kernel(const int* __restrict__ dst,
                                                    int E, int* __restrict__ cnt) {
    int e = blockIdx.x * 256 + threadIdx.x;
    if (e < E) atomicAdd(&cnt[dst[e]], 1);
}

// ---------------- 3-kernel exclusive scan over cnt[] -> row_start[] ----------------
__global__ __launch_bounds__(256) void scan1_kernel(const int* __restrict__ cnt, int n,
                                                    int* __restrict__ row_start,
                                                    int* __restrict__ bsum) {
    __shared__ int sdata[256];
    int tid = threadIdx.x;
    int i = blockIdx.x * 256 + tid;
    int v = (i < n) ? cnt[i] : 0;
    sdata[tid] = v;
    __syncthreads();
    for (int off = 1; off < 256; off <<= 1) {
        int t = (tid >= off) ? sdata[tid - off] : 0;
        __syncthreads();
        sdata[tid] += t;
        __syncthreads();
    }
    if (i < n) row_start[i] = sdata[tid] - v;  // exclusive, block-local
    if (tid == 255) bsum[blockIdx.x] = sdata[255];
}

__global__ __launch_bounds__(512) void scan2_kernel(int* __restrict__ bsum, int nb,
                                                    int* __restrict__ boff) {
    __shared__ int sdata[512];
    int tid = threadIdx.x;
    int v = (tid < nb) ? bsum[tid] : 0;
    sdata[tid] = v;
    __syncthreads();
    for (int off = 1; off < 512; off <<= 1) {
        int t = (tid >= off) ? sdata[tid - off] : 0;
        __syncthreads();
        sdata[tid] += t;
        __syncthreads();
    }
    boff[tid] = sdata[tid] - v;  // exclusive
}

__global__ __launch_bounds__(256) void scan3_kernel(int* __restrict__ row_start,
                                                    const int* __restrict__ boff,
                                                    const int* __restrict__ cnt,
                                                    int* __restrict__ cursor,
                                                    float* __restrict__ dinv,
                                                    int n, int E) {
    int i = blockIdx.x * 256 + threadIdx.x;
    if (i < n) {
        int rs = row_start[i] + boff[i >> 8];
        row_start[i] = rs;
        cursor[i] = rs;
        dinv[i] = rsqrtf((float)(cnt[i] + 1));  // +1 self loop
    }
    if (i == 0) row_start[n] = E;
}

// ---------------- CSR fill ----------------
__global__ __launch_bounds__(256) void fill_kernel(const int* __restrict__ src,
                                                   const int* __restrict__ dst,
                                                   int E, int* __restrict__ cursor,
                                                   int* __restrict__ csr_src) {
    int e = blockIdx.x * 256 + threadIdx.x;
    if (e < E) {
        int d = dst[e];
        int p = atomicAdd(&cursor[d], 1);
        csr_src[p] = src[e];
    }
}

// ---------------- GEMM: Y[n x NCOL] = X[n x 128] * W[128 x NCOL] ----------------
// 4 waves/block, 16 rows/wave (64 rows/block). Lane owns CPL = NCOL/64 cols.
// All lanes of a wave process the same row at once -> Xs reads are LDS
// broadcasts (same address). Bounded registers: acc 16*CPL + w 4*CPL + x 4.
template <int NCOL>
__global__ __launch_bounds__(256, 3) void gemm_kernel(const float* __restrict__ X,
                                                      const float* __restrict__ W,
                                                      float* __restrict__ Y, int nrows) {
    constexpr int K = 128;
    constexpr int KT = 32;               // K-tile for W staging
    constexpr int CPL = NCOL / 64;       // cols per lane (2 or 1)
    __shared__ __align__(16) float Xs[64 * K];      // 32 KB
    __shared__ __align__(16) float Ws[KT * NCOL];   // 16 KB / 8 KB

    int tid = threadIdx.x;
    int wave = tid >> 6;
    int lane = tid & 63;
    int rowBase = blockIdx.x * 64;
    int r0 = wave * 16;

    // stage X tile (64 rows x 128), coalesced float4
    {
        float4* Xs4 = (float4*)Xs;
        const float4* X4 = (const float4*)X;
        for (int j = tid; j < 64 * (K / 4); j += 256) {
            int r = j >> 5;       // /(K/4)=32
            int gr = rowBase + r;
            float4 v = make_float4(0.f, 0.f, 0.f, 0.f);
            if (gr < nrows) v = X4[(size_t)gr * (K / 4) + (j & 31)];
            Xs4[j] = v;
        }
    }

    float acc[16][CPL];
    #pragma unroll
    for (int r = 0; r < 16; r++)
        #pragma unroll
        for (int c = 0; c < CPL; c++) acc[r][c] = 0.f;

    #pragma unroll 1
    for (int kt = 0; kt < K; kt += KT) {
        __syncthreads();
        // stage W k-tile
        {
            float4* Ws4 = (float4*)Ws;
            const float4* W4 = (const float4*)W;
            for (int j = tid; j < KT * (NCOL / 4); j += 256)
                Ws4[j] = W4[(size_t)kt * (NCOL / 4) + j];
        }
        __syncthreads();
        #pragma unroll 2
        for (int k4 = 0; k4 < KT; k4 += 4) {
            float wv[4][CPL];
            #pragma unroll
            for (int kk = 0; kk < 4; kk++)
                #pragma unroll
                for (int c = 0; c < CPL; c++)
                    wv[kk][c] = Ws[(k4 + kk) * NCOL + lane * CPL + c];
            #pragma unroll
            for (int r = 0; r < 16; r++) {
                float4 xv = *(const float4*)&Xs[(r0 + r) * K + kt + k4];  // broadcast
                #pragma unroll
                for (int c = 0; c < CPL; c++) {
                    acc[r][c] = fmaf(xv.x, wv[0][c], acc[r][c]);
                    acc[r][c] = fmaf(xv.y, wv[1][c], acc[r][c]);
                    acc[r][c] = fmaf(xv.z, wv[2][c], acc[r][c]);
                    acc[r][c] = fmaf(xv.w, wv[3][c], acc[r][c]);
                }
            }
        }
    }

    #pragma unroll
    for (int r = 0; r < 16; r++) {
        int gr = rowBase + r0 + r;
        if (gr < nrows) {
            if (CPL == 2) {
                *(float2*)&Y[(size_t)gr * NCOL + lane * 2] =
                    make_float2(acc[r][0], acc[r][CPL - 1]);
            } else {
                Y[(size_t)gr * NCOL + lane] = acc[r][0];
            }
        }
    }
}

// ---------------- aggregation layer 1: pull + bias + relu + L2 rownorm ----------------
__global__ __launch_bounds__(256) void agg1_kernel(const float* __restrict__ xw,
                                                   const int* __restrict__ csr_src,
                                                   const int* __restrict__ row_start,
                                                   const float* __restrict__ dinv,
                                                   const float* __restrict__ b1,
                                                   float* __restrict__ h, int n) {
    int wid = (blockIdx.x * 256 + threadIdx.x) >> 6;  // one wave per node
    int lane = threadIdx.x & 63;
    if (wid >= n) return;
    int i = wid;
    float di = dinv[i];
    float sc = di * di;  // self-loop coef
    const float2* selfrow = (const float2*)(xw + (size_t)i * HID);
    float2 sv = selfrow[lane];
    float ax = sv.x * sc, ay = sv.y * sc;
    int e0 = row_start[i], e1 = row_start[i + 1];
    for (int e = e0; e < e1; e++) {
        int s = csr_src[e];
        float w = dinv[s] * di;
        float2 v = ((const float2*)(xw + (size_t)s * HID))[lane];
        ax = fmaf(v.x, w, ax);
        ay = fmaf(v.y, w, ay);
    }
    ax += b1[lane * 2];
    ay += b1[lane * 2 + 1];
    ax = fmaxf(ax, 0.f);
    ay = fmaxf(ay, 0.f);
    float ss = ax * ax + ay * ay;
    #pragma unroll
    for (int m = 32; m >= 1; m >>= 1) ss += __shfl_xor(ss, m, 64);
    float norm = sqrtf(ss);
    float scale = 1.0f / fmaxf(norm, 1e-12f);
    ((float2*)(h + (size_t)i * HID))[lane] = make_float2(ax * scale, ay * scale);
}

// ---------------- aggregation layer 2: pull + bias -> d_out ----------------
__global__ __launch_bounds__(256) void agg2_kernel(const float* __restrict__ hw,
                                                   const int* __restrict__ csr_src,
                                                   const int* __restrict__ row_start,
                                                   const float* __restrict__ dinv,
                                                   const float* __restrict__ b2,
                                                   float* __restrict__ out, int n) {
    int wid = (blockIdx.x * 256 + threadIdx.x) >> 6;  // one wave per node
    int lane = threadIdx.x & 63;
    if (wid >= n) return;
    int i = wid;
    float di = dinv[i];
    float sc = di * di;
    float a = hw[(size_t)i * OUT_CH + lane] * sc;
    int e0 = row_start[i], e1 = row_start[i + 1];
    for (int e = e0; e < e1; e++) {
        int s = csr_src[e];
        float w = dinv[s] * di;
        a = fmaf(hw[(size_t)s * OUT_CH + lane], w, a);
    }
    a += b2[lane];
    out[(size_t)i * OUT_CH + lane] = a;
}

extern "C" void kernel_launch(void* const* d_in, const int* in_sizes, int n_in,
                              void* d_out, int out_size, void* d_ws, size_t ws_size,
                              hipStream_t stream) {
    const float* x  = (const float*)d_in[0];
    const int*   ei = (const int*)d_in[1];   // [2 x E] int32 per harness convention
    const float* W1 = (const float*)d_in[2];
    const float* b1 = (const float*)d_in[3];
    const float* W2 = (const float*)d_in[4];
    const float* b2 = (const float*)d_in[5];
    float* out = (float*)d_out;

    const int N = in_sizes[0] / IN_CH;     // 100000
    const int E = in_sizes[1] / 2;         // 1600000
    const int* src = ei;
    const int* dst = ei + E;

    // ---- workspace carve (all 256B aligned) ----
    char* base = (char*)d_ws;
    size_t off = 0;
    auto alloc = [&](size_t bytes) -> void* {
        void* p = base + off;
        off = (off + bytes + 255) & ~(size_t)255;
        return p;
    };
    int*   cnt       = (int*)alloc((size_t)N * 4);
    int*   row_start = (int*)alloc((size_t)(N + 1) * 4);
    int*   cursor    = (int*)alloc((size_t)N * 4);
    int*   bsum      = (int*)alloc(512 * 4);
    int*   boff      = (int*)alloc(512 * 4);
    float* dinv      = (float*)alloc((size_t)N * 4);
    int*   csr_src   = (int*)alloc((size_t)E * 4);
    float* xw        = (float*)alloc((size_t)N * HID * 4);
    float* h         = (float*)alloc((size_t)N * HID * 4);
    float* hw        = (float*)alloc((size_t)N * OUT_CH * 4);
    (void)ws_size;

    const int nb = (N + 255) / 256;  // scan blocks (391)

    // 1) degree histogram
    hipMemsetAsync(cnt, 0, (size_t)N * 4, stream);
    count_kernel<<<(E + 255) / 256, 256, 0, stream>>>(dst, E, cnt);

    // 2) exclusive scan -> row_start; dinv; cursor
    scan1_kernel<<<nb, 256, 0, stream>>>(cnt, N, row_start, bsum);
    scan2_kernel<<<1, 512, 0, stream>>>(bsum, nb, boff);
    scan3_kernel<<<nb, 256, 0, stream>>>(row_start, boff, cnt, cursor, dinv, N, E);

    // 3) CSR fill
    fill_kernel<<<(E + 255) / 256, 256, 0, stream>>>(src, dst, E, cursor, csr_src);

    // 4) GEMM1: xw = x @ W1
    gemm_kernel<128><<<(N + 63) / 64, 256, 0, stream>>>(x, W1, xw, N);

    // 5) aggregate + bias + relu + rownorm -> h
    agg1_kernel<<<(N * 64 + 255) / 256, 256, 0, stream>>>(xw, csr_src, row_start, dinv, b1, h, N);

    // 6) GEMM2: hw = h @ W2
    gemm_kernel<64><<<(N + 63) / 64, 256, 0, stream>>>(h, W2, hw, N);

    // 7) aggregate + bias -> out
    agg2_kernel<<<(N * 64 + 255) / 256, 256, 0, stream>>>(hw, csr_src, row_start, dinv, b2, out, N);
}

// Round 3
// 577.237 us; speedup vs baseline: 4.4630x; 1.2551x over previous
//
#include <hip/hip_runtime.h>
#include <hip/hip_bf16.h>

// GCN encoder: 2x GCNConv with symmetric normalization, relu + L2 rownorm between.
// CSR-by-dst build (histogram + scan + fill w/ per-edge coef), pull aggregation.
// R2: agg loops were latency-bound (VALUBusy 22%) -- precompute edge coef,
// unroll gathers x8 for MLP, agg2 packs 2 nodes per wave.

#define IN_CH 128
#define HID 128
#define OUT_CH 64

// ---------------- degree histogram ----------------
__global__ __launch_bounds__(256) void count_kernel(const int* __restrict__ dst,
                                                    int E, int* __restrict__ cnt) {
    int e = blockIdx.x * 256 + threadIdx.x;
    if (e < E) atomicAdd(&cnt[dst[e]], 1);
}

// ---------------- 3-kernel exclusive scan over cnt[] -> row_start[] ----------------
__global__ __launch_bounds__(256) void scan1_kernel(const int* __restrict__ cnt, int n,
                                                    int* __restrict__ row_start,
                                                    int* __restrict__ bsum) {
    __shared__ int sdata[256];
    int tid = threadIdx.x;
    int i = blockIdx.x * 256 + tid;
    int v = (i < n) ? cnt[i] : 0;
    sdata[tid] = v;
    __syncthreads();
    for (int off = 1; off < 256; off <<= 1) {
        int t = (tid >= off) ? sdata[tid - off] : 0;
        __syncthreads();
        sdata[tid] += t;
        __syncthreads();
    }
    if (i < n) row_start[i] = sdata[tid] - v;  // exclusive, block-local
    if (tid == 255) bsum[blockIdx.x] = sdata[255];
}

__global__ __launch_bounds__(512) void scan2_kernel(int* __restrict__ bsum, int nb,
                                                    int* __restrict__ boff) {
    __shared__ int sdata[512];
    int tid = threadIdx.x;
    int v = (tid < nb) ? bsum[tid] : 0;
    sdata[tid] = v;
    __syncthreads();
    for (int off = 1; off < 512; off <<= 1) {
        int t = (tid >= off) ? sdata[tid - off] : 0;
        __syncthreads();
        sdata[tid] += t;
        __syncthreads();
    }
    boff[tid] = sdata[tid] - v;  // exclusive
}

__global__ __launch_bounds__(256) void scan3_kernel(int* __restrict__ row_start,
                                                    const int* __restrict__ boff,
                                                    const int* __restrict__ cnt,
                                                    int* __restrict__ cursor,
                                                    float* __restrict__ dinv,
                                                    int n, int E) {
    int i = blockIdx.x * 256 + threadIdx.x;
    if (i < n) {
        int rs = row_start[i] + boff[i >> 8];
        row_start[i] = rs;
        cursor[i] = rs;
        dinv[i] = rsqrtf((float)(cnt[i] + 1));  // +1 self loop
    }
    if (i == 0) row_start[n] = E;
}

// ---------------- CSR fill (+ per-edge coefficient) ----------------
__global__ __launch_bounds__(256) void fill_kernel(const int* __restrict__ src,
                                                   const int* __restrict__ dst,
                                                   int E, int* __restrict__ cursor,
                                                   const float* __restrict__ dinv,
                                                   int* __restrict__ csr_src,
                                                   float* __restrict__ csr_coef) {
    int e = blockIdx.x * 256 + threadIdx.x;
    if (e < E) {
        int s = src[e];
        int d = dst[e];
        int p = atomicAdd(&cursor[d], 1);
        csr_src[p] = s;
        csr_coef[p] = dinv[s] * dinv[d];
    }
}

// ---------------- GEMM: Y[n x NCOL] = X[n x 128] * W[128 x NCOL] ----------------
// 4 waves/block, 16 rows/wave. Xs reads are same-address LDS broadcasts.
template <int NCOL>
__global__ __launch_bounds__(256, 3) void gemm_kernel(const float* __restrict__ X,
                                                      const float* __restrict__ W,
                                                      float* __restrict__ Y, int nrows) {
    constexpr int K = 128;
    constexpr int KT = 32;               // K-tile for W staging
    constexpr int CPL = NCOL / 64;       // cols per lane (2 or 1)
    __shared__ __align__(16) float Xs[64 * K];      // 32 KB
    __shared__ __align__(16) float Ws[KT * NCOL];   // 16 KB / 8 KB

    int tid = threadIdx.x;
    int wave = tid >> 6;
    int lane = tid & 63;
    int rowBase = blockIdx.x * 64;
    int r0 = wave * 16;

    {
        float4* Xs4 = (float4*)Xs;
        const float4* X4 = (const float4*)X;
        for (int j = tid; j < 64 * (K / 4); j += 256) {
            int r = j >> 5;
            int gr = rowBase + r;
            float4 v = make_float4(0.f, 0.f, 0.f, 0.f);
            if (gr < nrows) v = X4[(size_t)gr * (K / 4) + (j & 31)];
            Xs4[j] = v;
        }
    }

    float acc[16][CPL];
    #pragma unroll
    for (int r = 0; r < 16; r++)
        #pragma unroll
        for (int c = 0; c < CPL; c++) acc[r][c] = 0.f;

    #pragma unroll 1
    for (int kt = 0; kt < K; kt += KT) {
        __syncthreads();
        {
            float4* Ws4 = (float4*)Ws;
            const float4* W4 = (const float4*)W;
            for (int j = tid; j < KT * (NCOL / 4); j += 256)
                Ws4[j] = W4[(size_t)kt * (NCOL / 4) + j];
        }
        __syncthreads();
        #pragma unroll 2
        for (int k4 = 0; k4 < KT; k4 += 4) {
            float wv[4][CPL];
            #pragma unroll
            for (int kk = 0; kk < 4; kk++)
                #pragma unroll
                for (int c = 0; c < CPL; c++)
                    wv[kk][c] = Ws[(k4 + kk) * NCOL + lane * CPL + c];
            #pragma unroll
            for (int r = 0; r < 16; r++) {
                float4 xv = *(const float4*)&Xs[(r0 + r) * K + kt + k4];  // broadcast
                #pragma unroll
                for (int c = 0; c < CPL; c++) {
                    acc[r][c] = fmaf(xv.x, wv[0][c], acc[r][c]);
                    acc[r][c] = fmaf(xv.y, wv[1][c], acc[r][c]);
                    acc[r][c] = fmaf(xv.z, wv[2][c], acc[r][c]);
                    acc[r][c] = fmaf(xv.w, wv[3][c], acc[r][c]);
                }
            }
        }
    }

    #pragma unroll
    for (int r = 0; r < 16; r++) {
        int gr = rowBase + r0 + r;
        if (gr < nrows) {
            if (CPL == 2) {
                *(float2*)&Y[(size_t)gr * NCOL + lane * 2] =
                    make_float2(acc[r][0], acc[r][CPL - 1]);
            } else {
                Y[(size_t)gr * NCOL + lane] = acc[r][0];
            }
        }
    }
}

// ---------------- aggregation layer 1: pull + bias + relu + L2 rownorm ----------------
// One wave per node, lane covers channels {2*lane, 2*lane+1}. Edge loop unrolled
// x8: batched index/coef loads then 8 independent gathers in flight.
__global__ __launch_bounds__(256) void agg1_kernel(const float* __restrict__ xw,
                                                   const int* __restrict__ csr_src,
                                                   const float* __restrict__ csr_coef,
                                                   const int* __restrict__ row_start,
                                                   const float* __restrict__ dinv,
                                                   const float* __restrict__ b1,
                                                   float* __restrict__ h, int n) {
    int wid = (blockIdx.x * 256 + threadIdx.x) >> 6;
    int lane = threadIdx.x & 63;
    if (wid >= n) return;
    int i = wid;
    float di = dinv[i];
    float sc = di * di;  // self-loop coef
    float2 sv = ((const float2*)(xw + (size_t)i * HID))[lane];
    float ax = sv.x * sc, ay = sv.y * sc;
    int e0 = row_start[i], e1 = row_start[i + 1];
    int e = e0;
    for (; e + 8 <= e1; e += 8) {
        int s[8];
        float c[8];
        #pragma unroll
        for (int j = 0; j < 8; j++) { s[j] = csr_src[e + j]; c[j] = csr_coef[e + j]; }
        float2 v[8];
        #pragma unroll
        for (int j = 0; j < 8; j++)
            v[j] = ((const float2*)(xw + (size_t)s[j] * HID))[lane];
        #pragma unroll
        for (int j = 0; j < 8; j++) {
            ax = fmaf(v[j].x, c[j], ax);
            ay = fmaf(v[j].y, c[j], ay);
        }
    }
    for (; e < e1; e++) {
        int s = csr_src[e];
        float c = csr_coef[e];
        float2 v = ((const float2*)(xw + (size_t)s * HID))[lane];
        ax = fmaf(v.x, c, ax);
        ay = fmaf(v.y, c, ay);
    }
    ax += b1[lane * 2];
    ay += b1[lane * 2 + 1];
    ax = fmaxf(ax, 0.f);
    ay = fmaxf(ay, 0.f);
    float ss = ax * ax + ay * ay;
    #pragma unroll
    for (int m = 32; m >= 1; m >>= 1) ss += __shfl_xor(ss, m, 64);
    float norm = sqrtf(ss);
    float scale = 1.0f / fmaxf(norm, 1e-12f);
    ((float2*)(h + (size_t)i * HID))[lane] = make_float2(ax * scale, ay * scale);
}

// ---------------- aggregation layer 2: pull + bias -> d_out ----------------
// Two nodes per wave: half-wave (32 lanes) per node, float2 per lane (64 ch).
__global__ __launch_bounds__(256) void agg2_kernel(const float* __restrict__ hw,
                                                   const int* __restrict__ csr_src,
                                                   const float* __restrict__ csr_coef,
                                                   const int* __restrict__ row_start,
                                                   const float* __restrict__ dinv,
                                                   const float* __restrict__ b2,
                                                   float* __restrict__ out, int n) {
    int wid = (blockIdx.x * 256 + threadIdx.x) >> 6;
    int lane = threadIdx.x & 63;
    int i = wid * 2 + (lane >> 5);
    int l = lane & 31;
    if (i >= n) return;
    float di = dinv[i];
    float sc = di * di;
    float2 a = ((const float2*)(hw + (size_t)i * OUT_CH))[l];
    a.x *= sc; a.y *= sc;
    int e0 = row_start[i], e1 = row_start[i + 1];
    int e = e0;
    for (; e + 8 <= e1; e += 8) {
        int s[8];
        float c[8];
        #pragma unroll
        for (int j = 0; j < 8; j++) { s[j] = csr_src[e + j]; c[j] = csr_coef[e + j]; }
        float2 v[8];
        #pragma unroll
        for (int j = 0; j < 8; j++)
            v[j] = ((const float2*)(hw + (size_t)s[j] * OUT_CH))[l];
        #pragma unroll
        for (int j = 0; j < 8; j++) {
            a.x = fmaf(v[j].x, c[j], a.x);
            a.y = fmaf(v[j].y, c[j], a.y);
        }
    }
    for (; e < e1; e++) {
        int s = csr_src[e];
        float c = csr_coef[e];
        float2 v = ((const float2*)(hw + (size_t)s * OUT_CH))[l];
        a.x = fmaf(v.x, c, a.x);
        a.y = fmaf(v.y, c, a.y);
    }
    a.x += b2[l * 2];
    a.y += b2[l * 2 + 1];
    ((float2*)(out + (size_t)i * OUT_CH))[l] = a;
}

extern "C" void kernel_launch(void* const* d_in, const int* in_sizes, int n_in,
                              void* d_out, int out_size, void* d_ws, size_t ws_size,
                              hipStream_t stream) {
    const float* x  = (const float*)d_in[0];
    const int*   ei = (const int*)d_in[1];
    const float* W1 = (const float*)d_in[2];
    const float* b1 = (const float*)d_in[3];
    const float* W2 = (const float*)d_in[4];
    const float* b2 = (const float*)d_in[5];
    float* out = (float*)d_out;

    const int N = in_sizes[0] / IN_CH;     // 100000
    const int E = in_sizes[1] / 2;         // 1600000
    const int* src = ei;
    const int* dst = ei + E;

    // ---- workspace carve ----
    char* base = (char*)d_ws;
    size_t off = 0;
    auto alloc = [&](size_t bytes) -> void* {
        void* p = base + off;
        off = (off + bytes + 255) & ~(size_t)255;
        return p;
    };
    int*   cnt       = (int*)alloc((size_t)N * 4);
    int*   row_start = (int*)alloc((size_t)(N + 1) * 4);
    int*   cursor    = (int*)alloc((size_t)N * 4);
    int*   bsum      = (int*)alloc(512 * 4);
    int*   boff      = (int*)alloc(512 * 4);
    float* dinv      = (float*)alloc((size_t)N * 4);
    int*   csr_src   = (int*)alloc((size_t)E * 4);
    float* csr_coef  = (float*)alloc((size_t)E * 4);
    float* xw        = (float*)alloc((size_t)N * HID * 4);
    float* h         = (float*)alloc((size_t)N * HID * 4);
    float* hw        = (float*)alloc((size_t)N * OUT_CH * 4);
    (void)ws_size;

    const int nb = (N + 255) / 256;

    hipMemsetAsync(cnt, 0, (size_t)N * 4, stream);
    count_kernel<<<(E + 255) / 256, 256, 0, stream>>>(dst, E, cnt);

    scan1_kernel<<<nb, 256, 0, stream>>>(cnt, N, row_start, bsum);
    scan2_kernel<<<1, 512, 0, stream>>>(bsum, nb, boff);
    scan3_kernel<<<nb, 256, 0, stream>>>(row_start, boff, cnt, cursor, dinv, N, E);

    fill_kernel<<<(E + 255) / 256, 256, 0, stream>>>(src, dst, E, cursor, dinv,
                                                     csr_src, csr_coef);

    gemm_kernel<128><<<(N + 63) / 64, 256, 0, stream>>>(x, W1, xw, N);

    agg1_kernel<<<(N * 64 + 255) / 256, 256, 0, stream>>>(xw, csr_src, csr_coef,
                                                          row_start, dinv, b1, h, N);

    gemm_kernel<64><<<(N + 63) / 64, 256, 0, stream>>>(h, W2, hw, N);

    int waves2 = (N + 1) / 2;
    agg2_kernel<<<(waves2 * 64 + 255) / 256, 256, 0, stream>>>(hw, csr_src, csr_coef,
                                                               row_start, dinv, b2, out, N);
}

// Round 4
// 531.751 us; speedup vs baseline: 4.8448x; 1.0855x over previous
//
#include <hip/hip_runtime.h>
#include <hip/hip_bf16.h>

// GCN encoder: 2x GCNConv, symmetric norm, relu + L2 rownorm between.
// CSR-by-dst build, pull aggregation (no float atomics).
// R3: intermediates xw/h/hw stored bf16 (f32 accumulate) -> halves gather +
// stream traffic; csr_coef dropped (agg loads dinv[s] batched); fill writes 4B/edge.

#define IN_CH 128
#define HID 128
#define OUT_CH 64

typedef unsigned int uint_t;
typedef unsigned short ushort_t;

__device__ __forceinline__ ushort_t f32_to_bf16_rn(float f) {
    uint_t u = __float_as_uint(f);
    u = (u + 0x7fffu + ((u >> 16) & 1u)) >> 16;
    return (ushort_t)u;
}
__device__ __forceinline__ float bf16lo_to_f32(uint_t u) { return __uint_as_float(u << 16); }
__device__ __forceinline__ float bf16hi_to_f32(uint_t u) { return __uint_as_float(u & 0xffff0000u); }

// ---------------- degree histogram ----------------
__global__ __launch_bounds__(256) void count_kernel(const int* __restrict__ dst,
                                                    int E, int* __restrict__ cnt) {
    int e = blockIdx.x * 256 + threadIdx.x;
    if (e < E) atomicAdd(&cnt[dst[e]], 1);
}

// ---------------- 3-kernel exclusive scan over cnt[] -> row_start[] ----------------
__global__ __launch_bounds__(256) void scan1_kernel(const int* __restrict__ cnt, int n,
                                                    int* __restrict__ row_start,
                                                    int* __restrict__ bsum) {
    __shared__ int sdata[256];
    int tid = threadIdx.x;
    int i = blockIdx.x * 256 + tid;
    int v = (i < n) ? cnt[i] : 0;
    sdata[tid] = v;
    __syncthreads();
    for (int off = 1; off < 256; off <<= 1) {
        int t = (tid >= off) ? sdata[tid - off] : 0;
        __syncthreads();
        sdata[tid] += t;
        __syncthreads();
    }
    if (i < n) row_start[i] = sdata[tid] - v;
    if (tid == 255) bsum[blockIdx.x] = sdata[255];
}

__global__ __launch_bounds__(512) void scan2_kernel(int* __restrict__ bsum, int nb,
                                                    int* __restrict__ boff) {
    __shared__ int sdata[512];
    int tid = threadIdx.x;
    int v = (tid < nb) ? bsum[tid] : 0;
    sdata[tid] = v;
    __syncthreads();
    for (int off = 1; off < 512; off <<= 1) {
        int t = (tid >= off) ? sdata[tid - off] : 0;
        __syncthreads();
        sdata[tid] += t;
        __syncthreads();
    }
    boff[tid] = sdata[tid] - v;
}

__global__ __launch_bounds__(256) void scan3_kernel(int* __restrict__ row_start,
                                                    const int* __restrict__ boff,
                                                    const int* __restrict__ cnt,
                                                    int* __restrict__ cursor,
                                                    float* __restrict__ dinv,
                                                    int n, int E) {
    int i = blockIdx.x * 256 + threadIdx.x;
    if (i < n) {
        int rs = row_start[i] + boff[i >> 8];
        row_start[i] = rs;
        cursor[i] = rs;
        dinv[i] = rsqrtf((float)(cnt[i] + 1));  // +1 self loop
    }
    if (i == 0) row_start[n] = E;
}

// ---------------- CSR fill (src index only) ----------------
__global__ __launch_bounds__(256) void fill_kernel(const int* __restrict__ src,
                                                   const int* __restrict__ dst,
                                                   int E, int* __restrict__ cursor,
                                                   int* __restrict__ csr_src) {
    int e = blockIdx.x * 256 + threadIdx.x;
    if (e < E) {
        int s = src[e];
        int d = dst[e];
        int p = atomicAdd(&cursor[d], 1);
        csr_src[p] = s;
    }
}

// ---------------- GEMM: Y[n x NCOL] = X[n x 128] * W[128 x NCOL] ----------------
// 4 waves/block, 16 rows/wave. Xs reads are same-address LDS broadcasts.
// X may be f32 or bf16 (converted during staging); Y written bf16 (RN-even).
template <int NCOL, bool BF16_IN>
__global__ __launch_bounds__(256, 3) void gemm_kernel(const void* __restrict__ Xv,
                                                      const float* __restrict__ W,
                                                      ushort_t* __restrict__ Y, int nrows) {
    constexpr int K = 128;
    constexpr int KT = 32;
    constexpr int CPL = NCOL / 64;       // cols per lane (2 or 1)
    __shared__ __align__(16) float Xs[64 * K];      // 32 KB
    __shared__ __align__(16) float Ws[KT * NCOL];   // 16 KB / 8 KB

    int tid = threadIdx.x;
    int wave = tid >> 6;
    int lane = tid & 63;
    int rowBase = blockIdx.x * 64;
    int r0 = wave * 16;

    if (BF16_IN) {
        const uint_t* X = (const uint_t*)Xv;   // 2 bf16 per uint, row stride K/2
        for (int j = tid; j < 64 * (K / 2); j += 256) {
            int r = j >> 6;            // /(K/2)=64
            int c = j & 63;
            int gr = rowBase + r;
            uint_t u = (gr < nrows) ? X[(size_t)gr * (K / 2) + c] : 0u;
            Xs[r * K + 2 * c]     = bf16lo_to_f32(u);
            Xs[r * K + 2 * c + 1] = bf16hi_to_f32(u);
        }
    } else {
        const float4* X4 = (const float4*)Xv;
        float4* Xs4 = (float4*)Xs;
        for (int j = tid; j < 64 * (K / 4); j += 256) {
            int r = j >> 5;
            int gr = rowBase + r;
            float4 v = make_float4(0.f, 0.f, 0.f, 0.f);
            if (gr < nrows) v = X4[(size_t)gr * (K / 4) + (j & 31)];
            Xs4[j] = v;
        }
    }

    float acc[16][CPL];
    #pragma unroll
    for (int r = 0; r < 16; r++)
        #pragma unroll
        for (int c = 0; c < CPL; c++) acc[r][c] = 0.f;

    #pragma unroll 1
    for (int kt = 0; kt < K; kt += KT) {
        __syncthreads();
        {
            float4* Ws4 = (float4*)Ws;
            const float4* W4 = (const float4*)W;
            for (int j = tid; j < KT * (NCOL / 4); j += 256)
                Ws4[j] = W4[(size_t)kt * (NCOL / 4) + j];
        }
        __syncthreads();
        #pragma unroll 2
        for (int k4 = 0; k4 < KT; k4 += 4) {
            float wv[4][CPL];
            #pragma unroll
            for (int kk = 0; kk < 4; kk++)
                #pragma unroll
                for (int c = 0; c < CPL; c++)
                    wv[kk][c] = Ws[(k4 + kk) * NCOL + lane * CPL + c];
            #pragma unroll
            for (int r = 0; r < 16; r++) {
                float4 xv = *(const float4*)&Xs[(r0 + r) * K + kt + k4];  // broadcast
                #pragma unroll
                for (int c = 0; c < CPL; c++) {
                    acc[r][c] = fmaf(xv.x, wv[0][c], acc[r][c]);
                    acc[r][c] = fmaf(xv.y, wv[1][c], acc[r][c]);
                    acc[r][c] = fmaf(xv.z, wv[2][c], acc[r][c]);
                    acc[r][c] = fmaf(xv.w, wv[3][c], acc[r][c]);
                }
            }
        }
    }

    #pragma unroll
    for (int r = 0; r < 16; r++) {
        int gr = rowBase + r0 + r;
        if (gr < nrows) {
            if (CPL == 2) {
                uint_t u = (uint_t)f32_to_bf16_rn(acc[r][0]) |
                           ((uint_t)f32_to_bf16_rn(acc[r][CPL - 1]) << 16);
                ((uint_t*)(Y + (size_t)gr * NCOL))[lane] = u;
            } else {
                Y[(size_t)gr * NCOL + lane] = f32_to_bf16_rn(acc[r][0]);
            }
        }
    }
}

// ---------------- aggregation layer 1: pull + bias + relu + L2 rownorm ----------------
// One wave per node, lane covers channels {2*lane, 2*lane+1} (one uint = 2 bf16).
__global__ __launch_bounds__(256) void agg1_kernel(const ushort_t* __restrict__ xw,
                                                   const int* __restrict__ csr_src,
                                                   const int* __restrict__ row_start,
                                                   const float* __restrict__ dinv,
                                                   const float* __restrict__ b1,
                                                   ushort_t* __restrict__ h, int n) {
    int wid = (blockIdx.x * 256 + threadIdx.x) >> 6;
    int lane = threadIdx.x & 63;
    if (wid >= n) return;
    int i = wid;
    float di = dinv[i];
    float sc = di * di;
    uint_t su = ((const uint_t*)(xw + (size_t)i * HID))[lane];
    float ax = bf16lo_to_f32(su) * sc, ay = bf16hi_to_f32(su) * sc;
    int e0 = row_start[i], e1 = row_start[i + 1];
    int e = e0;
    for (; e + 8 <= e1; e += 8) {
        int s[8];
        #pragma unroll
        for (int j = 0; j < 8; j++) s[j] = csr_src[e + j];
        float dv[8];
        #pragma unroll
        for (int j = 0; j < 8; j++) dv[j] = dinv[s[j]];
        uint_t v[8];
        #pragma unroll
        for (int j = 0; j < 8; j++)
            v[j] = ((const uint_t*)(xw + (size_t)s[j] * HID))[lane];
        #pragma unroll
        for (int j = 0; j < 8; j++) {
            float c = dv[j] * di;
            ax = fmaf(bf16lo_to_f32(v[j]), c, ax);
            ay = fmaf(bf16hi_to_f32(v[j]), c, ay);
        }
    }
    for (; e < e1; e++) {
        int s = csr_src[e];
        float c = dinv[s] * di;
        uint_t v = ((const uint_t*)(xw + (size_t)s * HID))[lane];
        ax = fmaf(bf16lo_to_f32(v), c, ax);
        ay = fmaf(bf16hi_to_f32(v), c, ay);
    }
    ax += b1[lane * 2];
    ay += b1[lane * 2 + 1];
    ax = fmaxf(ax, 0.f);
    ay = fmaxf(ay, 0.f);
    float ss = ax * ax + ay * ay;
    #pragma unroll
    for (int m = 32; m >= 1; m >>= 1) ss += __shfl_xor(ss, m, 64);
    float scale = 1.0f / fmaxf(sqrtf(ss), 1e-12f);
    uint_t u = (uint_t)f32_to_bf16_rn(ax * scale) |
               ((uint_t)f32_to_bf16_rn(ay * scale) << 16);
    ((uint_t*)(h + (size_t)i * HID))[lane] = u;
}

// ---------------- aggregation layer 2: pull + bias -> d_out (f32) ----------------
// Two nodes per wave: half-wave (32 lanes) per node, one uint (2 bf16) per lane.
__global__ __launch_bounds__(256) void agg2_kernel(const ushort_t* __restrict__ hw,
                                                   const int* __restrict__ csr_src,
                                                   const int* __restrict__ row_start,
                                                   const float* __restrict__ dinv,
                                                   const float* __restrict__ b2,
                                                   float* __restrict__ out, int n) {
    int wid = (blockIdx.x * 256 + threadIdx.x) >> 6;
    int lane = threadIdx.x & 63;
    int i = wid * 2 + (lane >> 5);
    int l = lane & 31;
    if (i >= n) return;
    float di = dinv[i];
    float sc = di * di;
    uint_t su = ((const uint_t*)(hw + (size_t)i * OUT_CH))[l];
    float ax = bf16lo_to_f32(su) * sc, ay = bf16hi_to_f32(su) * sc;
    int e0 = row_start[i], e1 = row_start[i + 1];
    int e = e0;
    for (; e + 8 <= e1; e += 8) {
        int s[8];
        #pragma unroll
        for (int j = 0; j < 8; j++) s[j] = csr_src[e + j];
        float dv[8];
        #pragma unroll
        for (int j = 0; j < 8; j++) dv[j] = dinv[s[j]];
        uint_t v[8];
        #pragma unroll
        for (int j = 0; j < 8; j++)
            v[j] = ((const uint_t*)(hw + (size_t)s[j] * OUT_CH))[l];
        #pragma unroll
        for (int j = 0; j < 8; j++) {
            float c = dv[j] * di;
            ax = fmaf(bf16lo_to_f32(v[j]), c, ax);
            ay = fmaf(bf16hi_to_f32(v[j]), c, ay);
        }
    }
    for (; e < e1; e++) {
        int s = csr_src[e];
        float c = dinv[s] * di;
        uint_t v = ((const uint_t*)(hw + (size_t)s * OUT_CH))[l];
        ax = fmaf(bf16lo_to_f32(v), c, ax);
        ay = fmaf(bf16hi_to_f32(v), c, ay);
    }
    ax += b2[l * 2];
    ay += b2[l * 2 + 1];
    ((float2*)(out + (size_t)i * OUT_CH))[l] = make_float2(ax, ay);
}

extern "C" void kernel_launch(void* const* d_in, const int* in_sizes, int n_in,
                              void* d_out, int out_size, void* d_ws, size_t ws_size,
                              hipStream_t stream) {
    const float* x  = (const float*)d_in[0];
    const int*   ei = (const int*)d_in[1];
    const float* W1 = (const float*)d_in[2];
    const float* b1 = (const float*)d_in[3];
    const float* W2 = (const float*)d_in[4];
    const float* b2 = (const float*)d_in[5];
    float* out = (float*)d_out;

    const int N = in_sizes[0] / IN_CH;     // 100000
    const int E = in_sizes[1] / 2;         // 1600000
    const int* src = ei;
    const int* dst = ei + E;

    // ---- workspace carve ----
    char* base = (char*)d_ws;
    size_t off = 0;
    auto alloc = [&](size_t bytes) -> void* {
        void* p = base + off;
        off = (off + bytes + 255) & ~(size_t)255;
        return p;
    };
    int*      cnt       = (int*)alloc((size_t)N * 4);
    int*      row_start = (int*)alloc((size_t)(N + 1) * 4);
    int*      cursor    = (int*)alloc((size_t)N * 4);
    int*      bsum      = (int*)alloc(512 * 4);
    int*      boff      = (int*)alloc(512 * 4);
    float*    dinv      = (float*)alloc((size_t)N * 4);
    int*      csr_src   = (int*)alloc((size_t)E * 4);
    ushort_t* xw        = (ushort_t*)alloc((size_t)N * HID * 2);
    ushort_t* h         = (ushort_t*)alloc((size_t)N * HID * 2);
    ushort_t* hw        = (ushort_t*)alloc((size_t)N * OUT_CH * 2);
    (void)ws_size;

    const int nb = (N + 255) / 256;

    hipMemsetAsync(cnt, 0, (size_t)N * 4, stream);
    count_kernel<<<(E + 255) / 256, 256, 0, stream>>>(dst, E, cnt);

    scan1_kernel<<<nb, 256, 0, stream>>>(cnt, N, row_start, bsum);
    scan2_kernel<<<1, 512, 0, stream>>>(bsum, nb, boff);
    scan3_kernel<<<nb, 256, 0, stream>>>(row_start, boff, cnt, cursor, dinv, N, E);

    fill_kernel<<<(E + 255) / 256, 256, 0, stream>>>(src, dst, E, cursor, csr_src);

    gemm_kernel<128, false><<<(N + 63) / 64, 256, 0, stream>>>(x, W1, xw, N);

    agg1_kernel<<<(N * 64 + 255) / 256, 256, 0, stream>>>(xw, csr_src, row_start,
                                                          dinv, b1, h, N);

    gemm_kernel<64, true><<<(N + 63) / 64, 256, 0, stream>>>(h, W2, hw, N);

    int waves2 = (N + 1) / 2;
    agg2_kernel<<<(waves2 * 64 + 255) / 256, 256, 0, stream>>>(hw, csr_src, row_start,
                                                               dinv, b2, out, N);
}

// Round 5
// 492.656 us; speedup vs baseline: 5.2293x; 1.0794x over previous
//
#include <hip/hip_runtime.h>
#include <hip/hip_bf16.h>

// GCN encoder: 2x GCNConv, symmetric norm, relu + L2 rownorm between.
// CSR-by-dst build, pull aggregation (no float atomics), bf16 intermediates.
// R4: fill_kernel had 16x write amplification (105MB WRITE for 6.4MB payload).
// Replaced with two-level bucket scatter: coarse (ticketed, write-local pair
// array, 64-node buckets) + fine (one block per bucket, LDS cursors).

#define IN_CH 128
#define HID 128
#define OUT_CH 64

typedef unsigned int uint_t;
typedef unsigned short ushort_t;

__device__ __forceinline__ ushort_t f32_to_bf16_rn(float f) {
    uint_t u = __float_as_uint(f);
    u = (u + 0x7fffu + ((u >> 16) & 1u)) >> 16;
    return (ushort_t)u;
}
__device__ __forceinline__ float bf16lo_to_f32(uint_t u) { return __uint_as_float(u << 16); }
__device__ __forceinline__ float bf16hi_to_f32(uint_t u) { return __uint_as_float(u & 0xffff0000u); }

// ---------------- degree histogram ----------------
__global__ __launch_bounds__(256) void count_kernel(const int* __restrict__ dst,
                                                    int E, int* __restrict__ cnt) {
    int e = blockIdx.x * 256 + threadIdx.x;
    if (e < E) atomicAdd(&cnt[dst[e]], 1);
}

// ---------------- 3-kernel exclusive scan over cnt[] -> row_start[] ----------------
__global__ __launch_bounds__(256) void scan1_kernel(const int* __restrict__ cnt, int n,
                                                    int* __restrict__ row_start,
                                                    int* __restrict__ bsum) {
    __shared__ int sdata[256];
    int tid = threadIdx.x;
    int i = blockIdx.x * 256 + tid;
    int v = (i < n) ? cnt[i] : 0;
    sdata[tid] = v;
    __syncthreads();
    for (int off = 1; off < 256; off <<= 1) {
        int t = (tid >= off) ? sdata[tid - off] : 0;
        __syncthreads();
        sdata[tid] += t;
        __syncthreads();
    }
    if (i < n) row_start[i] = sdata[tid] - v;
    if (tid == 255) bsum[blockIdx.x] = sdata[255];
}

__global__ __launch_bounds__(512) void scan2_kernel(int* __restrict__ bsum, int nb,
                                                    int* __restrict__ boff) {
    __shared__ int sdata[512];
    int tid = threadIdx.x;
    int v = (tid < nb) ? bsum[tid] : 0;
    sdata[tid] = v;
    __syncthreads();
    for (int off = 1; off < 512; off <<= 1) {
        int t = (tid >= off) ? sdata[tid - off] : 0;
        __syncthreads();
        sdata[tid] += t;
        __syncthreads();
    }
    boff[tid] = sdata[tid] - v;
}

__global__ __launch_bounds__(256) void scan3_kernel(int* __restrict__ row_start,
                                                    const int* __restrict__ boff,
                                                    const int* __restrict__ cnt,
                                                    float* __restrict__ dinv,
                                                    int n, int E) {
    int i = blockIdx.x * 256 + threadIdx.x;
    if (i < n) {
        int rs = row_start[i] + boff[i >> 8];
        row_start[i] = rs;
        dinv[i] = rsqrtf((float)(cnt[i] + 1));  // +1 self loop
    }
    if (i == 0) row_start[n] = E;
}

// ---------------- coarse scatter: edges -> bucket-ordered packed pairs ----------
// bucket = dst >> 6 (64 nodes). Ticketed write into pair region starting at
// row_start[dst & ~63]. Cursor padded to 64B (16 ints) to spread L2 lines.
// pack: src (26 bits) | (dst & 63) << 26.
__global__ __launch_bounds__(256) void coarse_scatter_kernel(const int* __restrict__ src,
                                                             const int* __restrict__ dst,
                                                             int E,
                                                             const int* __restrict__ row_start,
                                                             int* __restrict__ bcur,
                                                             uint_t* __restrict__ pairs) {
    int e = blockIdx.x * 256 + threadIdx.x;
    if (e < E) {
        int s = src[e];
        int d = dst[e];
        int b = d >> 6;
        int base = row_start[d & ~63];
        int p = atomicAdd(&bcur[b * 16], 1);
        pairs[base + p] = (uint_t)s | ((uint_t)(d & 63) << 26);
    }
}

// ---------------- fine fill: one block per bucket, LDS cursors ----------------
__global__ __launch_bounds__(256) void fine_fill_kernel(const uint_t* __restrict__ pairs,
                                                        const int* __restrict__ row_start,
                                                        int* __restrict__ csr_src,
                                                        int n) {
    __shared__ int cur[64];
    int b = blockIdx.x;
    int node0 = b << 6;
    int tid = threadIdx.x;
    if (tid < 64 && node0 + tid < n) cur[tid] = row_start[node0 + tid];
    __syncthreads();
    int start = row_start[node0];
    int nodeEnd = node0 + 64; if (nodeEnd > n) nodeEnd = n;
    int end = row_start[nodeEnd];
    for (int j = start + tid; j < end; j += 256) {
        uint_t u = pairs[j];
        int s = (int)(u & 0x3FFFFFFu);
        int dl = (int)(u >> 26);
        int pos = atomicAdd(&cur[dl], 1);
        csr_src[pos] = s;
    }
}

// ---------------- GEMM: Y[n x NCOL] = X[n x 128] * W[128 x NCOL] ----------------
template <int NCOL, bool BF16_IN>
__global__ __launch_bounds__(256, 3) void gemm_kernel(const void* __restrict__ Xv,
                                                      const float* __restrict__ W,
                                                      ushort_t* __restrict__ Y, int nrows) {
    constexpr int K = 128;
    constexpr int KT = 32;
    constexpr int CPL = NCOL / 64;       // cols per lane (2 or 1)
    __shared__ __align__(16) float Xs[64 * K];      // 32 KB
    __shared__ __align__(16) float Ws[KT * NCOL];   // 16 KB / 8 KB

    int tid = threadIdx.x;
    int wave = tid >> 6;
    int lane = tid & 63;
    int rowBase = blockIdx.x * 64;
    int r0 = wave * 16;

    if (BF16_IN) {
        const uint_t* X = (const uint_t*)Xv;
        for (int j = tid; j < 64 * (K / 2); j += 256) {
            int r = j >> 6;
            int c = j & 63;
            int gr = rowBase + r;
            uint_t u = (gr < nrows) ? X[(size_t)gr * (K / 2) + c] : 0u;
            Xs[r * K + 2 * c]     = bf16lo_to_f32(u);
            Xs[r * K + 2 * c + 1] = bf16hi_to_f32(u);
        }
    } else {
        const float4* X4 = (const float4*)Xv;
        float4* Xs4 = (float4*)Xs;
        for (int j = tid; j < 64 * (K / 4); j += 256) {
            int r = j >> 5;
            int gr = rowBase + r;
            float4 v = make_float4(0.f, 0.f, 0.f, 0.f);
            if (gr < nrows) v = X4[(size_t)gr * (K / 4) + (j & 31)];
            Xs4[j] = v;
        }
    }

    float acc[16][CPL];
    #pragma unroll
    for (int r = 0; r < 16; r++)
        #pragma unroll
        for (int c = 0; c < CPL; c++) acc[r][c] = 0.f;

    #pragma unroll 1
    for (int kt = 0; kt < K; kt += KT) {
        __syncthreads();
        {
            float4* Ws4 = (float4*)Ws;
            const float4* W4 = (const float4*)W;
            for (int j = tid; j < KT * (NCOL / 4); j += 256)
                Ws4[j] = W4[(size_t)kt * (NCOL / 4) + j];
        }
        __syncthreads();
        #pragma unroll 2
        for (int k4 = 0; k4 < KT; k4 += 4) {
            float wv[4][CPL];
            #pragma unroll
            for (int kk = 0; kk < 4; kk++)
                #pragma unroll
                for (int c = 0; c < CPL; c++)
                    wv[kk][c] = Ws[(k4 + kk) * NCOL + lane * CPL + c];
            #pragma unroll
            for (int r = 0; r < 16; r++) {
                float4 xv = *(const float4*)&Xs[(r0 + r) * K + kt + k4];  // broadcast
                #pragma unroll
                for (int c = 0; c < CPL; c++) {
                    acc[r][c] = fmaf(xv.x, wv[0][c], acc[r][c]);
                    acc[r][c] = fmaf(xv.y, wv[1][c], acc[r][c]);
                    acc[r][c] = fmaf(xv.z, wv[2][c], acc[r][c]);
                    acc[r][c] = fmaf(xv.w, wv[3][c], acc[r][c]);
                }
            }
        }
    }

    #pragma unroll
    for (int r = 0; r < 16; r++) {
        int gr = rowBase + r0 + r;
        if (gr < nrows) {
            if (CPL == 2) {
                uint_t u = (uint_t)f32_to_bf16_rn(acc[r][0]) |
                           ((uint_t)f32_to_bf16_rn(acc[r][CPL - 1]) << 16);
                ((uint_t*)(Y + (size_t)gr * NCOL))[lane] = u;
            } else {
                Y[(size_t)gr * NCOL + lane] = f32_to_bf16_rn(acc[r][0]);
            }
        }
    }
}

// ---------------- aggregation layer 1: pull + bias + relu + L2 rownorm ----------------
__global__ __launch_bounds__(256) void agg1_kernel(const ushort_t* __restrict__ xw,
                                                   const int* __restrict__ csr_src,
                                                   const int* __restrict__ row_start,
                                                   const float* __restrict__ dinv,
                                                   const float* __restrict__ b1,
                                                   ushort_t* __restrict__ h, int n) {
    int wid = (blockIdx.x * 256 + threadIdx.x) >> 6;
    int lane = threadIdx.x & 63;
    if (wid >= n) return;
    int i = wid;
    float di = dinv[i];
    float sc = di * di;
    uint_t su = ((const uint_t*)(xw + (size_t)i * HID))[lane];
    float ax = bf16lo_to_f32(su) * sc, ay = bf16hi_to_f32(su) * sc;
    int e0 = row_start[i], e1 = row_start[i + 1];
    int e = e0;
    for (; e + 8 <= e1; e += 8) {
        int s[8];
        #pragma unroll
        for (int j = 0; j < 8; j++) s[j] = csr_src[e + j];
        float dv[8];
        #pragma unroll
        for (int j = 0; j < 8; j++) dv[j] = dinv[s[j]];
        uint_t v[8];
        #pragma unroll
        for (int j = 0; j < 8; j++)
            v[j] = ((const uint_t*)(xw + (size_t)s[j] * HID))[lane];
        #pragma unroll
        for (int j = 0; j < 8; j++) {
            float c = dv[j] * di;
            ax = fmaf(bf16lo_to_f32(v[j]), c, ax);
            ay = fmaf(bf16hi_to_f32(v[j]), c, ay);
        }
    }
    for (; e < e1; e++) {
        int s = csr_src[e];
        float c = dinv[s] * di;
        uint_t v = ((const uint_t*)(xw + (size_t)s * HID))[lane];
        ax = fmaf(bf16lo_to_f32(v), c, ax);
        ay = fmaf(bf16hi_to_f32(v), c, ay);
    }
    ax += b1[lane * 2];
    ay += b1[lane * 2 + 1];
    ax = fmaxf(ax, 0.f);
    ay = fmaxf(ay, 0.f);
    float ss = ax * ax + ay * ay;
    #pragma unroll
    for (int m = 32; m >= 1; m >>= 1) ss += __shfl_xor(ss, m, 64);
    float scale = 1.0f / fmaxf(sqrtf(ss), 1e-12f);
    uint_t u = (uint_t)f32_to_bf16_rn(ax * scale) |
               ((uint_t)f32_to_bf16_rn(ay * scale) << 16);
    ((uint_t*)(h + (size_t)i * HID))[lane] = u;
}

// ---------------- aggregation layer 2: pull + bias -> d_out (f32) ----------------
__global__ __launch_bounds__(256) void agg2_kernel(const ushort_t* __restrict__ hw,
                                                   const int* __restrict__ csr_src,
                                                   const int* __restrict__ row_start,
                                                   const float* __restrict__ dinv,
                                                   const float* __restrict__ b2,
                                                   float* __restrict__ out, int n) {
    int wid = (blockIdx.x * 256 + threadIdx.x) >> 6;
    int lane = threadIdx.x & 63;
    int i = wid * 2 + (lane >> 5);
    int l = lane & 31;
    if (i >= n) return;
    float di = dinv[i];
    float sc = di * di;
    uint_t su = ((const uint_t*)(hw + (size_t)i * OUT_CH))[l];
    float ax = bf16lo_to_f32(su) * sc, ay = bf16hi_to_f32(su) * sc;
    int e0 = row_start[i], e1 = row_start[i + 1];
    int e = e0;
    for (; e + 8 <= e1; e += 8) {
        int s[8];
        #pragma unroll
        for (int j = 0; j < 8; j++) s[j] = csr_src[e + j];
        float dv[8];
        #pragma unroll
        for (int j = 0; j < 8; j++) dv[j] = dinv[s[j]];
        uint_t v[8];
        #pragma unroll
        for (int j = 0; j < 8; j++)
            v[j] = ((const uint_t*)(hw + (size_t)s[j] * OUT_CH))[l];
        #pragma unroll
        for (int j = 0; j < 8; j++) {
            float c = dv[j] * di;
            ax = fmaf(bf16lo_to_f32(v[j]), c, ax);
            ay = fmaf(bf16hi_to_f32(v[j]), c, ay);
        }
    }
    for (; e < e1; e++) {
        int s = csr_src[e];
        float c = dinv[s] * di;
        uint_t v = ((const uint_t*)(hw + (size_t)s * OUT_CH))[l];
        ax = fmaf(bf16lo_to_f32(v), c, ax);
        ay = fmaf(bf16hi_to_f32(v), c, ay);
    }
    ax += b2[l * 2];
    ay += b2[l * 2 + 1];
    ((float2*)(out + (size_t)i * OUT_CH))[l] = make_float2(ax, ay);
}

extern "C" void kernel_launch(void* const* d_in, const int* in_sizes, int n_in,
                              void* d_out, int out_size, void* d_ws, size_t ws_size,
                              hipStream_t stream) {
    const float* x  = (const float*)d_in[0];
    const int*   ei = (const int*)d_in[1];
    const float* W1 = (const float*)d_in[2];
    const float* b1 = (const float*)d_in[3];
    const float* W2 = (const float*)d_in[4];
    const float* b2 = (const float*)d_in[5];
    float* out = (float*)d_out;

    const int N = in_sizes[0] / IN_CH;     // 100000
    const int E = in_sizes[1] / 2;         // 1600000
    const int* src = ei;
    const int* dst = ei + E;
    const int NB = (N + 63) / 64;          // coarse buckets (1563)

    // ---- workspace carve ----
    char* base = (char*)d_ws;
    size_t off = 0;
    auto alloc = [&](size_t bytes) -> void* {
        void* p = base + off;
        off = (off + bytes + 255) & ~(size_t)255;
        return p;
    };
    int*      cnt       = (int*)alloc((size_t)N * 4);
    int*      row_start = (int*)alloc((size_t)(N + 1) * 4);
    int*      bsum      = (int*)alloc(512 * 4);
    int*      boff      = (int*)alloc(512 * 4);
    float*    dinv      = (float*)alloc((size_t)N * 4);
    int*      csr_src   = (int*)alloc((size_t)E * 4);
    uint_t*   pairs     = (uint_t*)alloc((size_t)E * 4);
    int*      bcur      = (int*)alloc((size_t)NB * 16 * 4);  // 64B-padded cursors
    ushort_t* xw        = (ushort_t*)alloc((size_t)N * HID * 2);
    ushort_t* h         = (ushort_t*)alloc((size_t)N * HID * 2);
    ushort_t* hw        = (ushort_t*)alloc((size_t)N * OUT_CH * 2);
    (void)ws_size;

    const int nb = (N + 255) / 256;

    hipMemsetAsync(cnt, 0, (size_t)N * 4, stream);
    hipMemsetAsync(bcur, 0, (size_t)NB * 16 * 4, stream);

    count_kernel<<<(E + 255) / 256, 256, 0, stream>>>(dst, E, cnt);

    scan1_kernel<<<nb, 256, 0, stream>>>(cnt, N, row_start, bsum);
    scan2_kernel<<<1, 512, 0, stream>>>(bsum, nb, boff);
    scan3_kernel<<<nb, 256, 0, stream>>>(row_start, boff, cnt, dinv, N, E);

    coarse_scatter_kernel<<<(E + 255) / 256, 256, 0, stream>>>(src, dst, E, row_start,
                                                               bcur, pairs);
    fine_fill_kernel<<<NB, 256, 0, stream>>>(pairs, row_start, csr_src, N);

    gemm_kernel<128, false><<<(N + 63) / 64, 256, 0, stream>>>(x, W1, xw, N);

    agg1_kernel<<<(N * 64 + 255) / 256, 256, 0, stream>>>(xw, csr_src, row_start,
                                                          dinv, b1, h, N);

    gemm_kernel<64, true><<<(N + 63) / 64, 256, 0, stream>>>(h, W2, hw, N);

    int waves2 = (N + 1) / 2;
    agg2_kernel<<<(waves2 * 64 + 255) / 256, 256, 0, stream>>>(hw, csr_src, row_start,
                                                               dinv, b2, out, N);
}